// Round 8
// baseline (8314.256 us; speedup 1.0000x reference)
//
#include <hip/hip_runtime.h>

// VectorQuantizer: N=262144 rows of D=64 fp32, K=1024 codebook rows.
// out = [x_quantized (N*D f32) | embed_inds (N, written as f32)]
//
// Bit-exact replication of np reference fp32 semantics (verified R4):
//   score(row,k) = fmaf(-2, seq-FMA-dot, fadd(xnorm, enorm)); argmin = first-min.
//
// Transposed structure (R6/R7) + VGPR-budget fix (R8):
//   R6/R7 both compiled to 128 VGPRs (spilling the 128-float codebook arrays,
//   21.8 GB scratch fetch) because the backend derives its occupancy target
//   from LDS-limited occupancy (76 KB -> 2 blocks/CU -> 4 waves/EU -> cap 128).
//   Fix: (a) amdgpu_waves_per_eu(2,2) pins target at 2 waves/EU (budget 256);
//        (b) LDS padded past 80 KB so even the default heuristic lands at
//            1 block/CU = 2 waves/EU. Either suffices.

static constexpr int D_DIM = 64;
static constexpr int K_CB  = 1024;
static constexpr int TPB   = 512;            // 8 waves
static constexpr int TILE  = 128;            // x rows per LDS tile (32 KB)
static constexpr int RPB   = 512;            // rows per block -> grid 512
static constexpr int NT    = RPB / TILE;     // 4 tiles

// numpy pairwise sum, n=64 path: 8 accumulators, sequential adds, fixed tree.
__device__ __forceinline__ float np_sum64_sq(const float* v) {
    float r[8];
#pragma unroll
    for (int j = 0; j < 8; ++j) r[j] = __fmul_rn(v[j], v[j]);
#pragma unroll
    for (int i = 8; i < 64; i += 8)
#pragma unroll
        for (int j = 0; j < 8; ++j) r[j] = __fadd_rn(r[j], __fmul_rn(v[i + j], v[i + j]));
    float t01 = __fadd_rn(r[0], r[1]), t23 = __fadd_rn(r[2], r[3]);
    float t45 = __fadd_rn(r[4], r[5]), t67 = __fadd_rn(r[6], r[7]);
    return __fadd_rn(__fadd_rn(t01, t23), __fadd_rn(t45, t67));
}

__global__ void __launch_bounds__(TPB)
__attribute__((amdgpu_waves_per_eu(2, 2)))
vq_kernel(
        const float* __restrict__ x, const float* __restrict__ cb,
        float* __restrict__ out_q, float* __restrict__ out_idx) {
    __shared__ float xt[2][TILE * D_DIM];   // 64 KB, double-buffered x tiles
    __shared__ float xnorm[RPB];            // 2 KB
    __shared__ float ps[8][TILE];           // per-wave partial scores
    __shared__ int   pk[8][TILE];           // per-wave partial indices
    __shared__ int   bks[TILE];
    __shared__ float lds_pad[1536];         // 6 KB: push LDS past 80 KB (see header)

    const int tid  = threadIdx.x;
    const int lane = tid & 63;
    const int w    = tid >> 6;
    const size_t brow0 = (size_t)blockIdx.x * RPB;

    // Touch the pad via volatile so it is allocated, never read.
    if (lane == 63) ((volatile float*)lds_pad)[w] = 0.f;

    // ---- phase 0a: x_norms for the block's rows (numpy pairwise order) ----
    {
        float tmp[D_DIM];
        const int r = tid;                   // RPB == TPB
        const float4* g = reinterpret_cast<const float4*>(x + (brow0 + r) * D_DIM);
#pragma unroll
        for (int c = 0; c < 16; ++c) {
            float4 v = g[c];
            tmp[4*c+0] = v.x; tmp[4*c+1] = v.y; tmp[4*c+2] = v.z; tmp[4*c+3] = v.w;
        }
        xnorm[r] = np_sum64_sq(tmp);
    }

    // ---- phase 0b: stage tile 0 (coalesced) ----
    {
        const float4* g = reinterpret_cast<const float4*>(x + brow0 * D_DIM);
        float4* dst = reinterpret_cast<float4*>(xt[0]);
#pragma unroll
        for (int i = 0; i < 4; ++i) dst[tid + TPB * i] = g[tid + TPB * i];
    }

    // ---- phase 0c: my 2 codebook rows -> 128 VGPRs; register e-norms ----
    float cbr0[D_DIM], cbr1[D_DIM];
    const int k0 = w * 128 + lane;
    const int k1 = k0 + 64;
    {
        const float4* g0 = reinterpret_cast<const float4*>(cb + (size_t)k0 * D_DIM);
        const float4* g1 = reinterpret_cast<const float4*>(cb + (size_t)k1 * D_DIM);
#pragma unroll
        for (int c = 0; c < 16; ++c) {
            float4 a = g0[c];
            cbr0[4*c+0] = a.x; cbr0[4*c+1] = a.y; cbr0[4*c+2] = a.z; cbr0[4*c+3] = a.w;
            float4 b = g1[c];
            cbr1[4*c+0] = b.x; cbr1[4*c+1] = b.y; cbr1[4*c+2] = b.z; cbr1[4*c+3] = b.w;
        }
    }
    const float en0 = np_sum64_sq(cbr0);
    const float en1 = np_sum64_sq(cbr1);

    __syncthreads();

    for (int t = 0; t < NT; ++t) {
        const int A = t & 1;
        const float* xtc = xt[A];

        // Prefetch next tile into registers now; LDS-write after main loop (T14).
        float4 pre[4];
        const bool hasNext = (t + 1 < NT);
        if (hasNext) {
            const float4* g = reinterpret_cast<const float4*>(
                x + (brow0 + (size_t)(t + 1) * TILE) * D_DIM);
#pragma unroll
            for (int i = 0; i < 4; ++i) pre[i] = g[tid + TPB * i];
        }

        // ---- main: 128 rows, batched by 4 for reduce-latency overlap ----
        for (int rb = 0; rb < TILE; rb += 4) {
            float ss[4]; int kk[4];
#pragma unroll
            for (int u = 0; u < 4; ++u) {
                const int r = rb + u;
                const float xn = xnorm[t * TILE + r];
                float d0 = 0.f, d1 = 0.f;
#pragma unroll
                for (int c = 0; c < 16; ++c) {
                    const float4 xv = *reinterpret_cast<const float4*>(&xtc[r * D_DIM + 4 * c]);
                    d0 = __fmaf_rn(xv.x, cbr0[4*c+0], d0);
                    d1 = __fmaf_rn(xv.x, cbr1[4*c+0], d1);
                    d0 = __fmaf_rn(xv.y, cbr0[4*c+1], d0);
                    d1 = __fmaf_rn(xv.y, cbr1[4*c+1], d1);
                    d0 = __fmaf_rn(xv.z, cbr0[4*c+2], d0);
                    d1 = __fmaf_rn(xv.z, cbr1[4*c+2], d1);
                    d0 = __fmaf_rn(xv.w, cbr0[4*c+3], d0);
                    d1 = __fmaf_rn(xv.w, cbr1[4*c+3], d1);
                }
                const float s0 = __fmaf_rn(-2.f, d0, __fadd_rn(xn, en0));
                const float s1 = __fmaf_rn(-2.f, d1, __fadd_rn(xn, en1));
                const bool take1 = (s1 < s0);       // tie -> s0 (k0 < k1)
                ss[u] = take1 ? s1 : s0;
                kk[u] = take1 ? k1 : k0;
            }
            // 4 interleaved butterfly reduces; exact first-min (index tie-break).
#pragma unroll
            for (int m = 1; m < 64; m <<= 1) {
#pragma unroll
                for (int u = 0; u < 4; ++u) {
                    const float s2 = __shfl_xor(ss[u], m);
                    const int   q2 = __shfl_xor(kk[u], m);
                    if (s2 < ss[u] || (s2 == ss[u] && q2 < kk[u])) { ss[u] = s2; kk[u] = q2; }
                }
            }
            if (lane == 0) {
#pragma unroll
                for (int u = 0; u < 4; ++u) { ps[w][rb + u] = ss[u]; pk[w][rb + u] = kk[u]; }
            }
        }

        // Write prefetched tile into the other buffer.
        if (hasNext) {
            float4* dst = reinterpret_cast<float4*>(xt[1 - A]);
#pragma unroll
            for (int i = 0; i < 4; ++i) dst[tid + TPB * i] = pre[i];
        }
        __syncthreads();

        // ---- merge 8 wave-partials per row (ascending w = ascending k) ----
        if (tid < TILE) {
            float b = ps[0][tid]; int bk = pk[0][tid];
#pragma unroll
            for (int ww = 1; ww < 8; ++ww) {
                const float s2 = ps[ww][tid]; const int q2 = pk[ww][tid];
                if (s2 < b) { b = s2; bk = q2; }   // tie keeps lower w (lower k)
            }
            bks[tid] = bk;
            out_idx[brow0 + (size_t)t * TILE + tid] = (float)bk;
        }
        __syncthreads();

        // ---- coalesced gather-write of x_quantized for this tile ----
        {
            const float4* cbg = reinterpret_cast<const float4*>(cb);
            float4* oq = reinterpret_cast<float4*>(out_q + (brow0 + (size_t)t * TILE) * D_DIM);
#pragma unroll
            for (int j = 0; j < 4; ++j) {
                const int f = tid + TPB * j;        // 0..2047
                const int r = f >> 4, c = f & 15;
                oq[f] = cbg[(size_t)bks[r] * 16 + c];
            }
        }
    }
}

extern "C" void kernel_launch(void* const* d_in, const int* in_sizes, int n_in,
                              void* d_out, int out_size, void* d_ws, size_t ws_size,
                              hipStream_t stream) {
    const float* x  = (const float*)d_in[0];
    const float* cb = (const float*)d_in[1];
    const int n_rows = in_sizes[0] / D_DIM;     // 262144

    float* out_q   = (float*)d_out;
    float* out_idx = out_q + (size_t)n_rows * D_DIM;

    vq_kernel<<<n_rows / RPB, TPB, 0, stream>>>(x, cb, out_q, out_idx);
}

// Round 9
// 719.812 us; speedup vs baseline: 11.5506x; 11.5506x over previous
//
#include <hip/hip_runtime.h>
#include <float.h>

// VectorQuantizer: N=262144 rows of D=64 fp32, K=1024 codebook rows.
// out = [x_quantized (N*D f32) | embed_inds (N, written as f32)]
//
// Bit-exact np-fp32 semantics (verified R4): score = fmaf(-2, seq-dot,
// fadd(xnorm, enorm)); pairwise-8 norms; strict < ascending k (first-min).
//
// R9: NO per-thread arrays (R4-R8 all failed SROA promotion -> scratch:
// R4 VGPR=40 < 64-float row; R6-R8 pinned at 128 + 21.8 GB scratch fetch).
// x-row = 16 named float4 vars. Codebook read at wave-uniform addresses
// (uniform k) -> scalar s_load into SGPRs, FMA takes SGPR operand: zero
// per-lane fetch traffic. es[k] once per block in LDS. Per-thread argmin.

static constexpr int D_DIM = 64;
static constexpr int K_CB  = 1024;
static constexpr int TPB   = 256;      // 1 thread = 1 row; 256 rows/block

// numpy pairwise-8 sum of squares of 64 values held as 16 float4s.
// r[j] (j=0..7) = a{x,y,z,w}, b{x,y,z,w}; init from (c0,c1), accumulate
// (c2,c3)..(c14,c15); tree ((r0+r1)+(r2+r3))+((r4+r5)+(r6+r7)).
#define NP_INIT(c0, c1)                                                     \
    float ax = __fmul_rn(c0.x, c0.x), ay = __fmul_rn(c0.y, c0.y),           \
          az = __fmul_rn(c0.z, c0.z), aw = __fmul_rn(c0.w, c0.w);           \
    float bx = __fmul_rn(c1.x, c1.x), by = __fmul_rn(c1.y, c1.y),           \
          bz = __fmul_rn(c1.z, c1.z), bw = __fmul_rn(c1.w, c1.w);
#define NP_ACC(ce, co)                                                      \
    ax = __fadd_rn(ax, __fmul_rn(ce.x, ce.x));                              \
    ay = __fadd_rn(ay, __fmul_rn(ce.y, ce.y));                              \
    az = __fadd_rn(az, __fmul_rn(ce.z, ce.z));                              \
    aw = __fadd_rn(aw, __fmul_rn(ce.w, ce.w));                              \
    bx = __fadd_rn(bx, __fmul_rn(co.x, co.x));                              \
    by = __fadd_rn(by, __fmul_rn(co.y, co.y));                              \
    bz = __fadd_rn(bz, __fmul_rn(co.z, co.z));                              \
    bw = __fadd_rn(bw, __fmul_rn(co.w, co.w));
#define NP_TREE()                                                           \
    __fadd_rn(__fadd_rn(__fadd_rn(ax, ay), __fadd_rn(az, aw)),              \
              __fadd_rn(__fadd_rn(bx, by), __fadd_rn(bz, bw)))

__device__ __forceinline__ float np_pair_sq16(
        float4 c0, float4 c1, float4 c2, float4 c3,
        float4 c4, float4 c5, float4 c6, float4 c7,
        float4 c8, float4 c9, float4 c10, float4 c11,
        float4 c12, float4 c13, float4 c14, float4 c15) {
    NP_INIT(c0, c1)
    NP_ACC(c2, c3)  NP_ACC(c4, c5)  NP_ACC(c6, c7)
    NP_ACC(c8, c9)  NP_ACC(c10, c11) NP_ACC(c12, c13) NP_ACC(c14, c15)
    return NP_TREE();
}

// One step of the sequential dot chain: d += cr[i] . x_i  (order-exact).
#define DOT4(i)                                                             \
    q = cr[i];                                                              \
    d = __fmaf_rn(q.x, x##i.x, d);                                          \
    d = __fmaf_rn(q.y, x##i.y, d);                                          \
    d = __fmaf_rn(q.z, x##i.z, d);                                          \
    d = __fmaf_rn(q.w, x##i.w, d);

__global__ void __launch_bounds__(TPB) vq_kernel(
        const float* __restrict__ x, const float* __restrict__ cb,
        float* __restrict__ out_q, float* __restrict__ out_idx) {
    __shared__ float es[K_CB];     // 4 KB
    __shared__ int bks[TPB];       // 1 KB

    const int tid = threadIdx.x;
    const size_t row0 = (size_t)blockIdx.x * TPB;
    const size_t row  = row0 + tid;
    const float4* cb4 = reinterpret_cast<const float4*>(cb);

    // ---- phase A: block-local e_norms (numpy pairwise order) ----
#pragma unroll
    for (int j = 0; j < K_CB / TPB; ++j) {
        const int k = tid + TPB * j;
        const float4* cr = cb4 + (size_t)k * 16;
        float4 c0 = cr[0],  c1 = cr[1],  c2 = cr[2],  c3 = cr[3],
               c4 = cr[4],  c5 = cr[5],  c6 = cr[6],  c7 = cr[7],
               c8 = cr[8],  c9 = cr[9],  c10 = cr[10], c11 = cr[11],
               c12 = cr[12], c13 = cr[13], c14 = cr[14], c15 = cr[15];
        es[k] = np_pair_sq16(c0, c1, c2, c3, c4, c5, c6, c7,
                             c8, c9, c10, c11, c12, c13, c14, c15);
    }
    __syncthreads();

    // ---- phase B: my row in 16 NAMED float4 registers; x_norm ----
    const float4* xg = reinterpret_cast<const float4*>(x + row * D_DIM);
    float4 x0 = xg[0],  x1 = xg[1],  x2 = xg[2],  x3 = xg[3],
           x4 = xg[4],  x5 = xg[5],  x6 = xg[6],  x7 = xg[7],
           x8 = xg[8],  x9 = xg[9],  x10 = xg[10], x11 = xg[11],
           x12 = xg[12], x13 = xg[13], x14 = xg[14], x15 = xg[15];
    const float xn = np_pair_sq16(x0, x1, x2, x3, x4, x5, x6, x7,
                                  x8, x9, x10, x11, x12, x13, x14, x15);

    // ---- phase C: k-scan; cb addresses wave-uniform -> scalar loads ----
    float best = FLT_MAX;
    int bestk = 0;
#pragma unroll 2
    for (int k = 0; k < K_CB; ++k) {
        const float4* cr = cb4 + (size_t)k * 16;
        float d = 0.f;
        float4 q;
        DOT4(0)  DOT4(1)  DOT4(2)  DOT4(3)
        DOT4(4)  DOT4(5)  DOT4(6)  DOT4(7)
        DOT4(8)  DOT4(9)  DOT4(10) DOT4(11)
        DOT4(12) DOT4(13) DOT4(14) DOT4(15)
        const float s = __fmaf_rn(-2.f, d, __fadd_rn(xn, es[k]));
        if (s < best) { best = s; bestk = k; }   // strict < = first-min
    }

    bks[tid] = bestk;
    __syncthreads();

    // ---- phase D: coalesced gather-write of x_quantized ----
    float4* oq = reinterpret_cast<float4*>(out_q + row0 * D_DIM);
#pragma unroll
    for (int j = 0; j < 16; ++j) {
        const int f = tid + TPB * j;     // 0..4095
        const int r = f >> 4, c = f & 15;
        oq[f] = cb4[(size_t)bks[r] * 16 + c];
    }
    out_idx[row] = (float)bestk;
}

extern "C" void kernel_launch(void* const* d_in, const int* in_sizes, int n_in,
                              void* d_out, int out_size, void* d_ws, size_t ws_size,
                              hipStream_t stream) {
    const float* x  = (const float*)d_in[0];
    const float* cb = (const float*)d_in[1];
    const int n_rows = in_sizes[0] / D_DIM;     // 262144

    float* out_q   = (float*)d_out;
    float* out_idx = out_q + (size_t)n_rows * D_DIM;

    vq_kernel<<<n_rows / TPB, TPB, 0, stream>>>(x, cb, out_q, out_idx);
}